// Round 7
// baseline (787.301 us; speedup 1.0000x reference)
//
#include <hip/hip_runtime.h>

// ---------------- problem constants ----------------
#define NN     4096
#define NE     131072
#define IN_CH  512
#define E_CH   64
#define HID    256
#define OUT_CH 16
#define KK     2
#define JJ     3
#define NB     5                      // K + J
#define REWEIGHT 0.6454972243679028f  // sqrt((64+256)/(512+256))

// output element offsets (fp32, concatenated in return order)
#define O_ADJ  0L
#define O_MU   50331648L
#define O_SG   50659328L
#define O_Z    50987008L
#define O_ZS   51183616L
#define O_EPS  51380224L
#define O_RK   51576832L
#define O_SNR  51576848L

__device__ __forceinline__ float fast_sigmoid(float x) {
    float e = __expf(-x);
    return __builtin_amdgcn_rcpf(1.f + e);
}

// ---------------- mega1: deg atomics | x@W1 | weight precompute ----------------
// blocks [0,512): deg; [512,1024): gemm_x; [1024,1043): precompute
// precompute: G = We@We^T (64x64), Wem = We@Wmu (64x16), Wes = We@Wsg,
//             bem = be@Wmu (16), bes = be@Wsg, vG = We@be (64), cbe = ||be||^2
__global__ void __launch_bounds__(256) k_mega1(
        const int* __restrict__ dst, int* __restrict__ degi,
        const float* __restrict__ x, const float* __restrict__ W1, float* __restrict__ h,
        const float* __restrict__ We, const float* __restrict__ Wmu,
        const float* __restrict__ Wsg, const float* __restrict__ be,
        float* __restrict__ G, float* __restrict__ Wem, float* __restrict__ Wes,
        float* __restrict__ bem, float* __restrict__ bes,
        float* __restrict__ vG, float* __restrict__ cbe) {
    int bid = blockIdx.x;
    int t = threadIdx.x;
    if (bid < 512) {
        int i = bid * 256 + t;
        atomicAdd(&degi[dst[i]], 1);
        return;
    }
    if (bid < 1024) {
        __shared__ float xs[8][IN_CH];
        long r0 = (long)(bid - 512) * 8;
        for (int idx = t; idx < 8 * IN_CH; idx += 256) {
            int rr = idx >> 9, k = idx & 511;
            xs[rr][k] = x[(r0 + rr) * IN_CH + k];
        }
        __syncthreads();
        float acc[8] = {};
#pragma unroll 4
        for (int k = 0; k < IN_CH; ++k) {
            float w = W1[k * HID + t];
#pragma unroll
            for (int rr = 0; rr < 8; ++rr) acc[rr] = fmaf(xs[rr][k], w, acc[rr]);
        }
#pragma unroll
        for (int rr = 0; rr < 8; ++rr) h[(r0 + rr) * HID + t] = acc[rr];
        return;
    }
    int wb = bid - 1024;
    if (wb < 16) {
        int r = wb * 4 + (t >> 6), c = t & 63;
        const float* wr = &We[(long)r * HID];
        const float* wc = &We[(long)c * HID];
        float s = 0.f;
#pragma unroll 4
        for (int o = 0; o < HID; ++o) s = fmaf(wr[o], wc[o], s);
        G[r * 64 + c] = s;
    } else if (wb < 18) {
        const float* Wx = (wb == 16) ? Wmu : Wsg;
        float* Wo = (wb == 16) ? Wem : Wes;
        float* bo = (wb == 16) ? bem : bes;
        int j = t & 15, c0 = t >> 4;
#pragma unroll
        for (int cc = 0; cc < 4; ++cc) {
            int c = c0 + cc * 16;
            const float* wc = &We[(long)c * HID];
            float s = 0.f;
            for (int o = 0; o < HID; ++o) s = fmaf(wc[o], Wx[o * OUT_CH + j], s);
            Wo[c * OUT_CH + j] = s;
        }
        if (t < 16) {
            float s = 0.f;
            for (int o = 0; o < HID; ++o) s = fmaf(be[o], Wx[o * OUT_CH + t], s);
            bo[t] = s;
        }
    } else {
        if (t < 64) {
            const float* wc = &We[(long)t * HID];
            float s = 0.f;
            for (int o = 0; o < HID; ++o) s = fmaf(wc[o], be[o], s);
            vG[t] = s;
        } else if (t == 64) {
            float s = 0.f;
            for (int o = 0; o < HID; ++o) s = fmaf(be[o], be[o], s);
            cbe[0] = s;
        }
    }
}

// ---------------- CSR scan + fill (unchanged) ----------------

__global__ void __launch_bounds__(1024) k_scan(const int* __restrict__ degi,
                       int* __restrict__ rowptr, int* __restrict__ cursor,
                       float* __restrict__ dinv) {
    __shared__ int sums[1024];
    int t = threadIdx.x;
    int d0[4], v[4];
    int s = 0;
#pragma unroll
    for (int i = 0; i < 4; ++i) { d0[i] = degi[t * 4 + i]; v[i] = s; s += d0[i]; }
    sums[t] = s;
    __syncthreads();
    for (int off = 1; off < 1024; off <<= 1) {
        int a = (t >= off) ? sums[t - off] : 0;
        __syncthreads();
        sums[t] += a;
        __syncthreads();
    }
    int base = (t > 0) ? sums[t - 1] : 0;
#pragma unroll
    for (int i = 0; i < 4; ++i) {
        rowptr[t * 4 + i] = base + v[i];
        cursor[t * 4 + i] = base + v[i];
        dinv[t * 4 + i] = rsqrtf((float)d0[i] + 1.0f);
    }
    if (t == 1023) rowptr[4096] = sums[1023];
}

__global__ void k_fill(const int* __restrict__ src, const int* __restrict__ dst,
                       const float* __restrict__ dinv,
                       int* __restrict__ cursor, int* __restrict__ esrc,
                       float* __restrict__ enorm) {
    int i = blockIdx.x * 256 + threadIdx.x;
    if (i >= NE) return;
    int s = src[i], d = dst[i];
    int pos = atomicAdd(&cursor[d], 1);
    esrc[pos] = s;
    enorm[pos] = dinv[s] * dinv[d];
}

// ---------------- mega2: hidden_x gather | e gather + u + noise-power ----------------
// blocks [0,4096): hidden_x = relu(gather + self + b1), sumsq -> psum[0]
// blocks [4096,5120): u = REWEIGHT*agg(e) (all NB per wave), store u,
//                     psum[1+b] += u@G@u^T + 2u.vG + cbe  (== ||u@We+be||^2)
__global__ void __launch_bounds__(256) k_mega2(
        const float* __restrict__ h, const int* __restrict__ rowptr,
        const int* __restrict__ esrc, const float* __restrict__ enorm,
        const float* __restrict__ dinv, const float* __restrict__ b1,
        float* __restrict__ hx, float* __restrict__ psum,
        const float* __restrict__ e, float* __restrict__ u,
        const float* __restrict__ G, const float* __restrict__ vG,
        const float* __restrict__ cbe) {
    __shared__ float gs[64][65];
    __shared__ float us[4][NB][64];
    __shared__ float red4[4];
    int bid = blockIdx.x;
    int t = threadIdx.x;
    if (bid < 4096) {
        int n = bid;
        int beg = rowptr[n], end = rowptr[n + 1];
        float dv = dinv[n];
        float acc = h[(long)n * HID + t] * dv * dv + b1[t];
        for (int j = beg; j < end; ++j)
            acc = fmaf(h[(long)esrc[j] * HID + t], enorm[j], acc);
        acc = fmaxf(acc, 0.f);
        hx[(long)n * HID + t] = acc;
        float sq = acc * acc;
#pragma unroll
        for (int off = 32; off; off >>= 1) sq += __shfl_down(sq, off, 64);
        if ((t & 63) == 0) red4[t >> 6] = sq;
        __syncthreads();
        if (t == 0) atomicAdd(&psum[0], red4[0] + red4[1] + red4[2] + red4[3]);
        return;
    }
    // ---- e branch ----
    for (int l = t; l < 64 * 64; l += 256) gs[l >> 6][l & 63] = G[l];
    int w = t >> 6;
    int n = (bid - 4096) * 4 + w;
    int c = t & 63;
    int beg = rowptr[n], end = rowptr[n + 1];
    float dv = dinv[n];
    float d2 = dv * dv;
    float ub[NB];
#pragma unroll
    for (int b = 0; b < NB; ++b) ub[b] = e[((long)b * NN + n) * E_CH + c] * d2;
    for (int j = beg; j < end; ++j) {
        int s = esrc[j];
        float wn = enorm[j];
        long base = (long)s * E_CH + c;
#pragma unroll
        for (int b = 0; b < NB; ++b)
            ub[b] = fmaf(e[(long)b * NN * E_CH + base], wn, ub[b]);
    }
#pragma unroll
    for (int b = 0; b < NB; ++b) {
        ub[b] *= REWEIGHT;
        u[((long)b * NN + n) * E_CH + c] = ub[b];
        us[w][b][c] = ub[b];
    }
    __syncthreads();
    float t5[NB] = {};
    for (int c2 = 0; c2 < 64; ++c2) {
        float g = gs[c][c2];
#pragma unroll
        for (int b = 0; b < NB; ++b) t5[b] = fmaf(g, us[w][b][c2], t5[b]);
    }
    float vr = vG[c];
    float cb = cbe[0];
#pragma unroll
    for (int b = 0; b < NB; ++b) {
        float r = ub[b] * (t5[b] + 2.f * vr);
#pragma unroll
        for (int off = 32; off; off >>= 1) r += __shfl_xor(r, off, 64);
        if (c == 0) atomicAdd(&psum[1 + b], r + cb);
    }
}

// ---------------- h_mu / h_sig via algebra: hx@W + u@(We@W) + be@W ----------------
__global__ void __launch_bounds__(256) k_gemm_ms(const float* __restrict__ hx,
                          const float* __restrict__ u,
                          const float* __restrict__ Wmu, const float* __restrict__ Wsg,
                          const float* __restrict__ Wem, const float* __restrict__ Wes,
                          const float* __restrict__ bem, const float* __restrict__ bes,
                          float* __restrict__ hmu, float* __restrict__ hsg) {
    int o = threadIdx.x & 15;
    int nn = threadIdx.x >> 4;
    int n = blockIdx.x * 16 + nn;
    int b = blockIdx.y;
    const float* px = &hx[(long)n * HID];
    const float* pu = &u[((long)b * NN + n) * E_CH];
    float amu = bem[o], asg = bes[o];
#pragma unroll 4
    for (int k = 0; k < HID; ++k) {
        float h1 = px[k];
        amu = fmaf(h1, Wmu[k * OUT_CH + o], amu);
        asg = fmaf(h1, Wsg[k * OUT_CH + o], asg);
    }
#pragma unroll 4
    for (int k = 0; k < E_CH; ++k) {
        float uv = pu[k];
        amu = fmaf(uv, Wem[k * OUT_CH + o], amu);
        asg = fmaf(uv, Wes[k * OUT_CH + o], asg);
    }
    long idx = ((long)b * NN + n) * OUT_CH + o;
    hmu[idx] = amu;
    hsg[idx] = asg;
}

// ---------------- agg16 + z + eps + rk + snr fused ----------------
__global__ void __launch_bounds__(256) k_agg16z(const int* __restrict__ rowptr,
        const int* __restrict__ esrc, const float* __restrict__ enorm,
        const float* __restrict__ dinv,
        const float* __restrict__ hmu, const float* __restrict__ hsg,
        const float* __restrict__ bmu, const float* __restrict__ bsg,
        const float* __restrict__ eps,
        float* __restrict__ omu, float* __restrict__ osg,
        float* __restrict__ oz, float* __restrict__ ozs, float* __restrict__ oeps,
        const float* __restrict__ rk_lgt, const float* __restrict__ psum,
        float* __restrict__ ork, float* __restrict__ osnr) {
    int p = blockIdx.x * 4 + (threadIdx.x >> 6);    // pair index: b*NN + n
    int lane = threadIdx.x & 63;
    int n = p & (NN - 1);
    int b = p >> 12;
    int es = lane >> 4, c = lane & 15;
    int beg = rowptr[n], end = rowptr[n + 1];
    const float* pm = &hmu[(long)b * NN * OUT_CH];
    const float* ps = &hsg[(long)b * NN * OUT_CH];
    float am = 0.f, as = 0.f;
    for (int j = beg + es; j < end; j += 4) {
        int s = esrc[j];
        float w = enorm[j];
        am = fmaf(pm[(long)s * OUT_CH + c], w, am);
        as = fmaf(ps[(long)s * OUT_CH + c], w, as);
    }
    am += __shfl_xor(am, 16, 64); as += __shfl_xor(as, 16, 64);
    am += __shfl_xor(am, 32, 64); as += __shfl_xor(as, 32, 64);
    float dv = dinv[n];
    float d2 = dv * dv;
    float vmu = am + pm[(long)n * OUT_CH + c] * d2 + bmu[c];
    float vsg = as + ps[(long)n * OUT_CH + c] * d2 + bsg[c];
    long base = ((long)b * NN + n) * OUT_CH;
    if (lane < 16) {
        omu[base + c] = vmu;
    } else if (lane < 32) {
        osg[base + c] = vsg;
    }
    if (b >= KK && lane < 16) {
        long zi = ((long)(b - KK) * NN + n) * OUT_CH + c;
        float ep = eps[zi];
        float zv = fmaf(ep, expf(0.5f * vsg), vmu);
        oz[zi] = zv; ozs[zi] = zv; oeps[zi] = ep;
    }
    if (blockIdx.x == 0 && threadIdx.x < 16 + NB) {
        int tt = threadIdx.x;
        if (tt < 16) ork[tt] = sqrtf(1.f / (1.f + expf(-rk_lgt[tt])));
        else osnr[tt - 16] = psum[0] / psum[1 + (tt - 16)];
    }
}

// ---------------- adj = sigmoid(z @ z^T) (unchanged) ----------------
__global__ void __launch_bounds__(256) k_adj(const float* __restrict__ z,
                                             float* __restrict__ adj) {
    __shared__ float zaT[16][132];
    __shared__ float zbT[16][132];
    int b  = blockIdx.z;
    int bi = blockIdx.y;
    int bj = blockIdx.x;
    const float* zbase = &z[(long)b * NN * OUT_CH];
    int tid = threadIdx.x;
    for (int l = tid; l < 128 * 16; l += 256) {
        int r = l >> 4, c = l & 15;
        zaT[c][r] = zbase[((long)bi * 128 + r) * OUT_CH + c];
        zbT[c][r] = zbase[((long)bj * 128 + r) * OUT_CH + c];
    }
    __syncthreads();
    int tr = tid >> 4, tc = tid & 15;
    float acc[8][8] = {};
#pragma unroll
    for (int d = 0; d < OUT_CH; ++d) {
        float4 a0 = *reinterpret_cast<const float4*>(&zaT[d][tr * 8]);
        float4 a1 = *reinterpret_cast<const float4*>(&zaT[d][tr * 8 + 4]);
        float4 b0 = *reinterpret_cast<const float4*>(&zbT[d][tc * 8]);
        float4 b1 = *reinterpret_cast<const float4*>(&zbT[d][tc * 8 + 4]);
        float av[8] = {a0.x, a0.y, a0.z, a0.w, a1.x, a1.y, a1.z, a1.w};
        float bv[8] = {b0.x, b0.y, b0.z, b0.w, b1.x, b1.y, b1.z, b1.w};
#pragma unroll
        for (int i = 0; i < 8; ++i)
#pragma unroll
            for (int j = 0; j < 8; ++j) acc[i][j] = fmaf(av[i], bv[j], acc[i][j]);
    }
#pragma unroll
    for (int i = 0; i < 8; ++i) {
        long row = (long)bi * 128 + tr * 8 + i;
        float* orow = &adj[((long)b * NN + row) * NN + (long)bj * 128 + tc * 8];
        float4 o0, o1;
        o0.x = fast_sigmoid(acc[i][0]); o0.y = fast_sigmoid(acc[i][1]);
        o0.z = fast_sigmoid(acc[i][2]); o0.w = fast_sigmoid(acc[i][3]);
        o1.x = fast_sigmoid(acc[i][4]); o1.y = fast_sigmoid(acc[i][5]);
        o1.z = fast_sigmoid(acc[i][6]); o1.w = fast_sigmoid(acc[i][7]);
        *reinterpret_cast<float4*>(&orow[0]) = o0;
        *reinterpret_cast<float4*>(&orow[4]) = o1;
    }
}

// ---------------- launch ----------------

extern "C" void kernel_launch(void* const* d_in, const int* in_sizes, int n_in,
                              void* d_out, int out_size, void* d_ws, size_t ws_size,
                              hipStream_t stream) {
    const float* x      = (const float*)d_in[0];
    const int*   eidx   = (const int*)d_in[1];
    const float* enoise = (const float*)d_in[2];
    const float* eps    = (const float*)d_in[3];
    const float* W1     = (const float*)d_in[4];
    const float* b1     = (const float*)d_in[5];
    const float* We     = (const float*)d_in[6];
    const float* be     = (const float*)d_in[7];
    const float* Wmu    = (const float*)d_in[8];
    const float* bmu    = (const float*)d_in[9];
    const float* Wsg    = (const float*)d_in[10];
    const float* bsg    = (const float*)d_in[11];
    const float* rk_lgt = (const float*)d_in[12];

    const int* src = eidx;
    const int* dst = eidx + NE;

    float* out = (float*)d_out;
    char*  wsb = (char*)d_ws;

    // workspace layout (degi+psum adjacent for single memset)
    int*   degi   = (int*)wsb;                         // 4096
    float* psum   = (float*)(degi + 4096);             // 16
    int*   rowptr = (int*)(psum + 16);                 // 4097
    int*   cursor = rowptr + 4097 + 3;                 // 4096 (8-align pad)
    int*   esrc   = cursor + 4096;                     // NE
    float* enorm  = (float*)(esrc + NE);               // NE
    float* dinv   = enorm + NE;                        // 4096
    float* h_x    = dinv + 4096;                       // N*HID
    float* hx     = h_x + (long)NN * HID;              // N*HID
    float* u      = hx + (long)NN * HID;               // NB*N*E_CH
    float* hmu    = u + (long)NB * NN * E_CH;          // NB*N*OUT
    float* hsg    = hmu + (long)NB * NN * OUT_CH;      // NB*N*OUT
    float* G      = hsg + (long)NB * NN * OUT_CH;      // 64*64
    float* Wem    = G + 64 * 64;                       // 64*16
    float* Wes    = Wem + 64 * OUT_CH;                 // 64*16
    float* bem    = Wes + 64 * OUT_CH;                 // 16
    float* bes    = bem + OUT_CH;                      // 16
    float* vG     = bes + OUT_CH;                      // 64
    float* cbe    = vG + 64;                           // 1

    float* omu = out + O_MU;
    float* osg = out + O_SG;

    // 1) zero degi + psum in one shot (adjacent)
    hipMemsetAsync(degi, 0, 4112 * sizeof(int), stream);

    // 2) deg | x@W1 | weight precompute
    k_mega1<<<1043, 256, 0, stream>>>(dst, degi, x, W1, h_x,
                                      We, Wmu, Wsg, be,
                                      G, Wem, Wes, bem, bes, vG, cbe);

    // 3) scan -> rowptr/cursor/dinv
    k_scan<<<1, 1024, 0, stream>>>(degi, rowptr, cursor, dinv);

    // 4) CSR fill
    k_fill<<<NE / 256, 256, 0, stream>>>(src, dst, dinv, cursor, esrc, enorm);

    // 5) hidden_x gather | e gather + u + noise power
    k_mega2<<<4096 + NN / 4, 256, 0, stream>>>(h_x, rowptr, esrc, enorm, dinv, b1,
                                               hx, psum, enoise, u, G, vG, cbe);

    // 6) h_mu / h_sg
    k_gemm_ms<<<dim3(NN / 16, NB), 256, 0, stream>>>(hx, u, Wmu, Wsg, Wem, Wes,
                                                     bem, bes, hmu, hsg);

    // 7) mu/sigma aggregation + z + eps + rk + snr
    k_agg16z<<<NB * NN / 4, 256, 0, stream>>>(rowptr, esrc, enorm, dinv,
                                              hmu, hsg, bmu, bsg, eps,
                                              omu, osg,
                                              out + O_Z, out + O_ZS, out + O_EPS,
                                              rk_lgt, psum, out + O_RK, out + O_SNR);

    // 8) adj
    k_adj<<<dim3(NN / 128, NN / 128, JJ), 256, 0, stream>>>(out + O_Z, out);
}